// Round 1
// baseline (379.127 us; speedup 1.0000x reference)
//
#include <hip/hip_runtime.h>

// Problem constants (fixed by the reference).
#define BB 8
#define CI 8
#define CO 8
#define DD 32
#define HH 128
#define WW 128
#define HW (HH * WW)

// One thread: 8 consecutive w positions x all 8 c_out = 64 outputs.
// Block: 256 threads = 16 w-tiles (full W=128) x 16 h rows.
// Grid: B * D * (H/16) = 8*32*8 = 2048 blocks.
__global__ __launch_bounds__(256) void conv3d_act_kernel(
    const float* __restrict__ x,
    const float* __restrict__ wgt,
    const float* __restrict__ bias,
    float* __restrict__ out)
{
    const int tid = threadIdx.x;
    const int wt  = tid & 15;   // w-tile index, 0..15
    const int hl  = tid >> 4;   // local h row, 0..15

    int bx = blockIdx.x;
    const int hb = bx & 7;          // H/16 = 8
    bx >>= 3;
    const int d  = bx & 31;         // D = 32
    const int b  = bx >> 5;         // B = 8

    const int h  = hb * 16 + hl;
    const int w0 = wt * 8;

    float acc[64];
    #pragma unroll
    for (int i = 0; i < 64; ++i) acc[i] = 0.f;

    const float* xb = x + (size_t)b * CI * DD * HW;

    for (int ci = 0; ci < CI; ++ci) {
        const float* xc = xb + ci * DD * HW;
        #pragma unroll
        for (int kd = 0; kd < 3; ++kd) {
            const int dd = d + kd - 1;
            if ((unsigned)dd >= DD) continue;           // block-uniform branch
            const float* xd = xc + dd * HW;
            #pragma unroll
            for (int kh = 0; kh < 3; ++kh) {
                const int hh = h + kh - 1;
                const bool vrow = (unsigned)hh < HH;    // divergent only at block h-edges
                const float* row = xd + hh * WW + w0;

                float4 A  = make_float4(0.f, 0.f, 0.f, 0.f);
                float4 Bv = make_float4(0.f, 0.f, 0.f, 0.f);
                float  xl = 0.f, xr = 0.f;
                if (vrow) {
                    A  = *(const float4*)(row);         // w0 .. w0+3 (16B aligned: w0 % 8 == 0)
                    Bv = *(const float4*)(row + 4);     // w0+4 .. w0+7
                    if (wt > 0)  xl = row[-1];          // left halo (zero-pad at w=0)
                    if (wt < 15) xr = row[8];           // right halo (zero-pad at w=127)
                }
                float xv[10] = {xl, A.x, A.y, A.z, A.w, Bv.x, Bv.y, Bv.z, Bv.w, xr};

                // 3*8*8 = 192 FMAs; weight index is wave-uniform -> s_load + v_fmac(v,s,v)
                #pragma unroll
                for (int kw = 0; kw < 3; ++kw) {
                    #pragma unroll
                    for (int co = 0; co < 8; ++co) {
                        const float wv = wgt[((co * CI + ci) * 3 + kd) * 9 + kh * 3 + kw];
                        #pragma unroll
                        for (int w = 0; w < 8; ++w)
                            acc[co * 8 + w] = fmaf(xv[w + kw], wv, acc[co * 8 + w]);
                    }
                }
            }
        }
    }

    // Epilogue: relu -> (leaky_relu == identity after relu) -> tanh-GELU -> sigmoid -> +bias[c]
    const size_t obase = (size_t)b * CO * DD * HW + (size_t)d * HW + (size_t)h * WW + w0;
    #pragma unroll
    for (int co = 0; co < 8; ++co) {
        const float bco = bias[co];
        float r[8];
        #pragma unroll
        for (int w = 0; w < 8; ++w) {
            float y = fmaxf(acc[co * 8 + w], 0.f);
            // t = sqrt(2/pi) * (y + 0.044715 y^3); gelu = y * (1 - 1/(1+e^{2t}))
            float t = 0.7978845608028654f * (y + 0.044715f * y * y * y);
            float e = __builtin_amdgcn_exp2f(2.8853900817779268f * t);   // e^{2t}
            float g = y - y * __builtin_amdgcn_rcpf(1.f + e);
            // sigmoid(g) = 1 / (1 + e^{-g})
            float s = __builtin_amdgcn_rcpf(1.f + __builtin_amdgcn_exp2f(-1.4426950408889634f * g));
            r[w] = s + bco;
        }
        float* orow = out + obase + (size_t)co * DD * HW;
        *(float4*)(orow)     = make_float4(r[0], r[1], r[2], r[3]);
        *(float4*)(orow + 4) = make_float4(r[4], r[5], r[6], r[7]);
    }
}

extern "C" void kernel_launch(void* const* d_in, const int* in_sizes, int n_in,
                              void* d_out, int out_size, void* d_ws, size_t ws_size,
                              hipStream_t stream) {
    const float* x    = (const float*)d_in[0];
    const float* wgt  = (const float*)d_in[1];
    const float* bias = (const float*)d_in[2];
    float* out = (float*)d_out;

    dim3 grid(BB * DD * (HH / 16));   // 2048 blocks
    dim3 block(256);
    conv3d_act_kernel<<<grid, block, 0, stream>>>(x, wgt, bias, out);
}